// Round 10
// baseline (165.671 us; speedup 1.0000x reference)
//
#include <hip/hip_runtime.h>
#include <hip/hip_cooperative_groups.h>

namespace cg = cooperative_groups;

// VQWeightedAvgPool: out[b,d] = sum_l w[b,l] * feat[b, N-1, l, d]
// w[b,l] = 1 / (n_seg_b * seg_len_b(l)) for l < len_b, else 0.
// feat (B=16, N=13, L=2048, D=768) f32; lengths (B,) int; vq (B, L, 2) int.
//
// Primary: ONE cooperative kernel (512 blocks x 192):
//   P0: blocks 0..15 scan batch blk -> w; others prefetch 16 rows of their
//       first tile (issued during the scan window).
//   P1: R7 pooling (SUBS=32, 2 tiles max, register acc, plain part store).
//   P2: blocks 0..15 reduce 32 partials -> out.
// Fallback (if coop launch rejected): exact R7 3-kernel path.

#define L_SEQ 2048
#define D_DIM 768
#define N_DIM 13
#define B_DIM 16
#define LT 32
#define MAX_TILES (L_SEQ / LT)   // 64
#define SUBS 32
#define GRID_B (B_DIM * SUBS)    // 512
#define BLK 192
#define SCAN_T 128
#define PER (L_SEQ / SCAN_T)     // 16
#define PRE_ROWS 16

// ============================ cooperative kernel ============================
__global__ __launch_bounds__(BLK, 2) void vq_coop(
    const float* __restrict__ feat,
    const int* __restrict__ lengths,
    const int* __restrict__ vq,
    float* __restrict__ w,
    float* __restrict__ part,
    float* __restrict__ out) {
  cg::grid_group grid = cg::this_grid();

  __shared__ int s_seg[L_SEQ];
  __shared__ int s_cnt[L_SEQ];
  __shared__ int s_wsum[2];

  const int blk = blockIdx.x;
  const int tid = threadIdx.x;
  const bool scanb = blk < B_DIM;

  const int b = blk >> 5;
  const int sub = blk & (SUBS - 1);
  const int len = lengths[b];
  int nt = (len + LT - 1) / LT;
  if (nt > MAX_TILES) nt = MAX_TILES;
  const bool valid = sub < nt;

  const float* fb = feat + ((size_t)b * N_DIM + (N_DIM - 1)) * L_SEQ * D_DIM;

  // ---- P0a: prefetch first PRE_ROWS rows of first tile (non-scan blocks) ----
  float4 pre[PRE_ROWS];
  if (!scanb && valid) {
    const float* basep = fb + (size_t)sub * LT * D_DIM + tid * 4;
#pragma unroll
    for (int i = 0; i < PRE_ROWS; ++i)
      pre[i] = *(const float4*)(basep + (size_t)i * D_DIM);
  }

  // ---- P0b: segment weights (blocks 0..15 scan batch = blk) ----
  if (scanb) {
    const int sb = blk;
    const int slen = lengths[sb];
    const int* vqb = vq + (size_t)sb * L_SEQ * 2;

    int flags[PER];
    int v = 0, lsum = 0, wid = 0;
    if (tid < SCAN_T) {
      const int lane = tid & 63;
      wid = tid >> 6;
      int4 q[PER / 2];
      const int4* v4 = (const int4*)vqb;
#pragma unroll
      for (int i = 0; i < PER / 2; ++i) q[i] = v4[(PER / 2) * tid + i];
      int cx[PER], cy[PER];
#pragma unroll
      for (int i = 0; i < PER / 2; ++i) {
        cx[2 * i] = q[i].x; cy[2 * i] = q[i].y;
        cx[2 * i + 1] = q[i].z; cy[2 * i + 1] = q[i].w;
      }
      int px = 0, py = 0;
      if (tid > 0) {
        const int2 pp = *(const int2*)(vqb + 2 * PER * tid - 2);
        px = pp.x; py = pp.y;
      }
      const int base = tid * PER;
#pragma unroll
      for (int i = 0; i < PER; ++i) {
        const int l = base + i;
        int bd = 0;
        if (l < slen) {
          if (l == 0) {
            bd = 1;
          } else {
            const int prx = (i == 0) ? px : cx[i - 1];
            const int pry = (i == 0) ? py : cy[i - 1];
            bd = (cx[i] != prx) || (cy[i] != pry);
          }
        }
        lsum += bd;
        flags[i] = lsum;
      }
      v = lsum;
      for (int off = 1; off < 64; off <<= 1) {
        int n = __shfl_up(v, off, 64);
        if (lane >= off) v += n;
      }
      if (lane == 63) s_wsum[wid] = v;
    }
    for (int l = tid; l < L_SEQ; l += BLK) s_cnt[l] = 0;
    __syncthreads();

    const int nseg = s_wsum[0] + s_wsum[1];
    if (tid < SCAN_T) {
      const int excl = (wid ? s_wsum[0] : 0) + (v - lsum);
      const int base = tid * PER;
#pragma unroll
      for (int i = 0; i < PER; ++i) s_seg[base + i] = excl + flags[i];
    }
    __syncthreads();

    for (int l = tid; l < L_SEQ; l += BLK)
      if (l < slen) atomicAdd(&s_cnt[s_seg[l] - 1], 1);
    __syncthreads();

    const float nsegf = (float)nseg;
    for (int l = tid; l < L_SEQ; l += BLK) {
      float wv = 0.0f;
      if (l < slen) {
        const float denom = fmaxf(nsegf * (float)s_cnt[s_seg[l] - 1], 1.0f);
        wv = 1.0f / denom;
      }
      w[(size_t)sb * L_SEQ + l] = wv;
    }
  }

  grid.sync();  // w visible device-wide

  // ---- P1: pooling (R7 structure) ----
  const float* wb = w + (size_t)b * L_SEQ;
  float4 acc = make_float4(0.f, 0.f, 0.f, 0.f);
  if (valid) {
    {  // first tile
      const float4* wb4 = (const float4*)(wb + sub * LT);
      float wl[LT];
#pragma unroll
      for (int i = 0; i < LT / 4; ++i) {
        const float4 wv = wb4[i];
        wl[4 * i + 0] = wv.x;
        wl[4 * i + 1] = wv.y;
        wl[4 * i + 2] = wv.z;
        wl[4 * i + 3] = wv.w;
      }
      const float* basep = fb + (size_t)sub * LT * D_DIM + tid * 4;
      if (scanb) {
#pragma unroll
        for (int i = 0; i < LT; ++i) {
          const float4 vx = *(const float4*)(basep + (size_t)i * D_DIM);
          acc.x += wl[i] * vx.x;
          acc.y += wl[i] * vx.y;
          acc.z += wl[i] * vx.z;
          acc.w += wl[i] * vx.w;
        }
      } else {
#pragma unroll
        for (int i = 0; i < PRE_ROWS; ++i) {
          acc.x += wl[i] * pre[i].x;
          acc.y += wl[i] * pre[i].y;
          acc.z += wl[i] * pre[i].z;
          acc.w += wl[i] * pre[i].w;
        }
#pragma unroll
        for (int i = PRE_ROWS; i < LT; ++i) {
          const float4 vx = *(const float4*)(basep + (size_t)i * D_DIM);
          acc.x += wl[i] * vx.x;
          acc.y += wl[i] * vx.y;
          acc.z += wl[i] * vx.z;
          acc.w += wl[i] * vx.w;
        }
      }
    }
    for (int t = sub + SUBS; t < nt; t += SUBS) {  // second tile (if any)
      const int l0 = t * LT;
      const float4* wb4 = (const float4*)(wb + l0);
      float wl[LT];
#pragma unroll
      for (int i = 0; i < LT / 4; ++i) {
        const float4 wv = wb4[i];
        wl[4 * i + 0] = wv.x;
        wl[4 * i + 1] = wv.y;
        wl[4 * i + 2] = wv.z;
        wl[4 * i + 3] = wv.w;
      }
      const float* basep = fb + (size_t)l0 * D_DIM + tid * 4;
#pragma unroll
      for (int i = 0; i < LT; ++i) {
        const float4 vx = *(const float4*)(basep + (size_t)i * D_DIM);
        acc.x += wl[i] * vx.x;
        acc.y += wl[i] * vx.y;
        acc.z += wl[i] * vx.z;
        acc.w += wl[i] * vx.w;
      }
    }
  }
  *(float4*)(part + (size_t)blk * D_DIM + tid * 4) = acc;

  grid.sync();  // partials visible device-wide

  // ---- P2: reduce (blocks 0..15; block = batch, thread = f4 slot) ----
  if (blk < B_DIM) {
    const float* p = part + ((size_t)blk * SUBS) * D_DIM + tid * 4;
    float4 a = make_float4(0.f, 0.f, 0.f, 0.f);
#pragma unroll
    for (int s = 0; s < SUBS; ++s) {
      const float4 vv = *(const float4*)(p + (size_t)s * D_DIM);
      a.x += vv.x;
      a.y += vv.y;
      a.z += vv.z;
      a.w += vv.w;
    }
    *(float4*)(out + (size_t)blk * D_DIM + tid * 4) = a;
  }
}

// ============================ fallback: R7 path ============================
#define BLK_A 256
#define PER_A 8

__global__ __launch_bounds__(BLK_A) void vq_weights_kernel(
    const int* __restrict__ lengths,
    const int* __restrict__ vq,
    float* __restrict__ w) {
  __shared__ int s_seg[L_SEQ];
  __shared__ int s_cnt[L_SEQ];
  __shared__ int s_wsum[4];

  const int b = blockIdx.x;
  const int tid = threadIdx.x;
  const int lane = tid & 63;
  const int wid = tid >> 6;
  const int len = lengths[b];
  const int* vqb = vq + (size_t)b * L_SEQ * 2;

  int4 q[4];
  const int4* v4 = (const int4*)vqb;
#pragma unroll
  for (int i = 0; i < 4; ++i) q[i] = v4[4 * tid + i];
  int px = 0, py = 0;
  if (tid > 0) {
    const int2 pp = *(const int2*)(vqb + 16 * tid - 2);
    px = pp.x; py = pp.y;
  }
  int cx[PER_A], cy[PER_A];
  cx[0] = q[0].x; cy[0] = q[0].y; cx[1] = q[0].z; cy[1] = q[0].w;
  cx[2] = q[1].x; cy[2] = q[1].y; cx[3] = q[1].z; cy[3] = q[1].w;
  cx[4] = q[2].x; cy[4] = q[2].y; cx[5] = q[2].z; cy[5] = q[2].w;
  cx[6] = q[3].x; cy[6] = q[3].y; cx[7] = q[3].z; cy[7] = q[3].w;

  int flags[PER_A];
  const int base = tid * PER_A;
  int lsum = 0;
#pragma unroll
  for (int i = 0; i < PER_A; ++i) {
    const int l = base + i;
    int bd = 0;
    if (l < len) {
      if (l == 0) {
        bd = 1;
      } else {
        const int prx = (i == 0) ? px : cx[i - 1];
        const int pry = (i == 0) ? py : cy[i - 1];
        bd = (cx[i] != prx) || (cy[i] != pry);
      }
    }
    lsum += bd;
    flags[i] = lsum;
  }

  int v = lsum;
  for (int off = 1; off < 64; off <<= 1) {
    int n = __shfl_up(v, off, 64);
    if (lane >= off) v += n;
  }
  if (lane == 63) s_wsum[wid] = v;
  __syncthreads();

  int woff = 0;
#pragma unroll
  for (int i = 0; i < 4; ++i)
    if (i < wid) woff += s_wsum[i];
  const int nseg = s_wsum[0] + s_wsum[1] + s_wsum[2] + s_wsum[3];
  const int excl = woff + (v - lsum);

#pragma unroll
  for (int i = 0; i < PER_A; ++i) s_seg[base + i] = excl + flags[i];
  for (int l = tid; l < L_SEQ; l += BLK_A) s_cnt[l] = 0;
  __syncthreads();

  for (int l = tid; l < L_SEQ; l += BLK_A)
    if (l < len) atomicAdd(&s_cnt[s_seg[l] - 1], 1);
  __syncthreads();

  const float nsegf = (float)nseg;
  for (int l = tid; l < L_SEQ; l += BLK_A) {
    float wv = 0.0f;
    if (l < len) {
      const float denom = fmaxf(nsegf * (float)s_cnt[s_seg[l] - 1], 1.0f);
      wv = 1.0f / denom;
    }
    w[(size_t)b * L_SEQ + l] = wv;
  }
}

__global__ __launch_bounds__(192) void vq_pool_kernel(
    const float* __restrict__ feat,
    const int* __restrict__ lengths,
    const float* __restrict__ w,
    float* __restrict__ part) {
  const int b = blockIdx.x >> 5;
  const int sub = blockIdx.x & (SUBS - 1);
  const int tid = threadIdx.x;
  const int len = lengths[b];
  int nt = (len + LT - 1) / LT;
  if (nt > MAX_TILES) nt = MAX_TILES;

  const float* fb = feat + ((size_t)b * N_DIM + (N_DIM - 1)) * L_SEQ * D_DIM;
  const float* wb = w + (size_t)b * L_SEQ;

  float4 acc = make_float4(0.f, 0.f, 0.f, 0.f);
  for (int t = sub; t < nt; t += SUBS) {
    const int l0 = t * LT;
    const float4* wb4 = (const float4*)(wb + l0);
    float wl[LT];
#pragma unroll
    for (int i = 0; i < LT / 4; ++i) {
      const float4 wv = wb4[i];
      wl[4 * i + 0] = wv.x;
      wl[4 * i + 1] = wv.y;
      wl[4 * i + 2] = wv.z;
      wl[4 * i + 3] = wv.w;
    }
    const float* basep = fb + (size_t)l0 * D_DIM + tid * 4;
#pragma unroll
    for (int i = 0; i < LT; ++i) {
      const float4 vx = *(const float4*)(basep + (size_t)i * D_DIM);
      acc.x += wl[i] * vx.x;
      acc.y += wl[i] * vx.y;
      acc.z += wl[i] * vx.z;
      acc.w += wl[i] * vx.w;
    }
  }
  *(float4*)(part + (size_t)blockIdx.x * D_DIM + tid * 4) = acc;
}

__global__ __launch_bounds__(64) void vq_reduce_kernel(
    const float* __restrict__ part,
    float* __restrict__ out) {
  const int slot = blockIdx.x * 64 + threadIdx.x;
  const int b = slot / (D_DIM / 4);
  const int d4 = slot - b * (D_DIM / 4);

  const float* p = part + ((size_t)b * SUBS) * D_DIM + d4 * 4;
  float4 acc = make_float4(0.f, 0.f, 0.f, 0.f);
#pragma unroll
  for (int s = 0; s < SUBS; ++s) {
    const float4 v = *(const float4*)(p + (size_t)s * D_DIM);
    acc.x += v.x;
    acc.y += v.y;
    acc.z += v.z;
    acc.w += v.w;
  }
  *(float4*)(out + (size_t)b * D_DIM + d4 * 4) = acc;
}

extern "C" void kernel_launch(void* const* d_in, const int* in_sizes, int n_in,
                              void* d_out, int out_size, void* d_ws, size_t ws_size,
                              hipStream_t stream) {
  const float* feat = (const float*)d_in[0];
  const int* lengths = (const int*)d_in[1];
  const int* vq = (const int*)d_in[2];
  float* out = (float*)d_out;
  float* w = (float*)d_ws;                  // B*L floats = 128 KiB
  float* part = w + (size_t)B_DIM * L_SEQ;  // 512*768 floats = 1.5 MiB

  void* args[] = {(void*)&feat, (void*)&lengths, (void*)&vq,
                  (void*)&w, (void*)&part, (void*)&out};
  hipError_t err = hipLaunchCooperativeKernel((void*)vq_coop, dim3(GRID_B),
                                              dim3(BLK), args, 0, stream);
  if (err != hipSuccess) {
    (void)hipGetLastError();  // clear sticky error, fall back to R7 path
    vq_weights_kernel<<<B_DIM, BLK_A, 0, stream>>>(lengths, vq, w);
    vq_pool_kernel<<<GRID_B, BLK, 0, stream>>>(feat, lengths, w, part);
    vq_reduce_kernel<<<(B_DIM * D_DIM / 4) / 64, 64, 0, stream>>>(part, out);
  }
}

// Round 11
// 73.104 us; speedup vs baseline: 2.2662x; 2.2662x over previous
//
#include <hip/hip_runtime.h>

// VQWeightedAvgPool: out[b,d] = sum_l w[b,l] * feat[b, N-1, l, d]
// w[b,l] = 1 / (n_seg_b * seg_len_b(l)) for l < len_b, else 0.
// feat (B=16, N=13, L=2048, D=768) f32; lengths (B,) int; vq (B, L, 2) int.
//
// 2 kernels: A (weights + zero tickets, 16 blocks), B (R7 pooling partials,
// plain stores; LAST block per batch [fence+ticket] reduces 32 partials -> out).

#define L_SEQ 2048
#define D_DIM 768
#define N_DIM 13
#define B_DIM 16
#define BLK_A 256
#define PER_A 8                  // 2048 / 256
#define LT 32                    // L-rows per pooling tile
#define MAX_TILES (L_SEQ / LT)   // 64
#define SUBS 32                  // pooling blocks per batch
#define GRID_B (B_DIM * SUBS)    // 512

// ---------------- Kernel A: per-batch segment weights (R7-exact) ------------
__global__ __launch_bounds__(BLK_A) void vq_weights_kernel(
    const int* __restrict__ lengths,
    const int* __restrict__ vq,
    float* __restrict__ w,
    int* __restrict__ tickets) {
  __shared__ int s_seg[L_SEQ];   // inclusive cumsum of boundary (= seg_id+1)
  __shared__ int s_cnt[L_SEQ];   // per-segment valid counts
  __shared__ int s_wsum[4];

  const int b = blockIdx.x;
  const int tid = threadIdx.x;
  const int lane = tid & 63;
  const int wid = tid >> 6;
  const int len = lengths[b];
  const int* vqb = vq + (size_t)b * L_SEQ * 2;

  if (tid == 0) tickets[b] = 0;  // re-zeroed every call (replay-safe)

  // vectorized pair loads: thread t owns l in [8t, 8t+8)
  int4 q[4];
  const int4* v4 = (const int4*)vqb;
#pragma unroll
  for (int i = 0; i < 4; ++i) q[i] = v4[4 * tid + i];
  int px = 0, py = 0;
  if (tid > 0) {
    const int2 pp = *(const int2*)(vqb + 16 * tid - 2);  // pair of l = 8t-1
    px = pp.x; py = pp.y;
  }
  int cx[PER_A], cy[PER_A];
  cx[0] = q[0].x; cy[0] = q[0].y; cx[1] = q[0].z; cy[1] = q[0].w;
  cx[2] = q[1].x; cy[2] = q[1].y; cx[3] = q[1].z; cy[3] = q[1].w;
  cx[4] = q[2].x; cy[4] = q[2].y; cx[5] = q[2].z; cy[5] = q[2].w;
  cx[6] = q[3].x; cy[6] = q[3].y; cx[7] = q[3].z; cy[7] = q[3].w;

  int flags[PER_A];
  const int base = tid * PER_A;
  int lsum = 0;
#pragma unroll
  for (int i = 0; i < PER_A; ++i) {
    const int l = base + i;
    int bd = 0;
    if (l < len) {
      if (l == 0) {
        bd = 1;
      } else {
        const int prx = (i == 0) ? px : cx[i - 1];
        const int pry = (i == 0) ? py : cy[i - 1];
        bd = (cx[i] != prx) || (cy[i] != pry);
      }
    }
    lsum += bd;
    flags[i] = lsum;
  }

  int v = lsum;
  for (int off = 1; off < 64; off <<= 1) {
    int n = __shfl_up(v, off, 64);
    if (lane >= off) v += n;
  }
  if (lane == 63) s_wsum[wid] = v;
  __syncthreads();

  int woff = 0;
#pragma unroll
  for (int i = 0; i < 4; ++i)
    if (i < wid) woff += s_wsum[i];
  const int nseg = s_wsum[0] + s_wsum[1] + s_wsum[2] + s_wsum[3];
  const int excl = woff + (v - lsum);

#pragma unroll
  for (int i = 0; i < PER_A; ++i) s_seg[base + i] = excl + flags[i];
  for (int l = tid; l < L_SEQ; l += BLK_A) s_cnt[l] = 0;
  __syncthreads();

  for (int l = tid; l < L_SEQ; l += BLK_A)
    if (l < len) atomicAdd(&s_cnt[s_seg[l] - 1], 1);
  __syncthreads();

  const float nsegf = (float)nseg;
  for (int l = tid; l < L_SEQ; l += BLK_A) {
    float wv = 0.0f;
    if (l < len) {
      const float denom = fmaxf(nsegf * (float)s_cnt[s_seg[l] - 1], 1.0f);
      wv = 1.0f / denom;
    }
    w[(size_t)b * L_SEQ + l] = wv;
  }
}

// ---------------- Kernel B: pooling + fused last-block reduce ---------------
// 512 blocks: (b = blk>>5, sub = blk&31), R7-exact pooling. After the
// partial store, per-batch fence+ticket; 32nd block reduces -> out[b].
__global__ __launch_bounds__(192) void vq_pool_kernel(
    const float* __restrict__ feat,
    const int* __restrict__ lengths,
    const float* __restrict__ w,
    float* __restrict__ part,
    int* __restrict__ tickets,
    float* __restrict__ out) {
  const int b = blockIdx.x >> 5;
  const int sub = blockIdx.x & (SUBS - 1);
  const int tid = threadIdx.x;
  const int len = lengths[b];
  int nt = (len + LT - 1) / LT;
  if (nt > MAX_TILES) nt = MAX_TILES;

  const float* fb = feat + ((size_t)b * N_DIM + (N_DIM - 1)) * L_SEQ * D_DIM;
  const float* wb = w + (size_t)b * L_SEQ;

  float4 acc = make_float4(0.f, 0.f, 0.f, 0.f);
  for (int t = sub; t < nt; t += SUBS) {
    const int l0 = t * LT;
    const float4* wb4 = (const float4*)(wb + l0);
    float wl[LT];
#pragma unroll
    for (int i = 0; i < LT / 4; ++i) {
      const float4 wv = wb4[i];
      wl[4 * i + 0] = wv.x;
      wl[4 * i + 1] = wv.y;
      wl[4 * i + 2] = wv.z;
      wl[4 * i + 3] = wv.w;
    }
    const float* basep = fb + (size_t)l0 * D_DIM + tid * 4;
#pragma unroll
    for (int i = 0; i < LT; ++i) {
      const float4 vx = *(const float4*)(basep + (size_t)i * D_DIM);
      acc.x += wl[i] * vx.x;
      acc.y += wl[i] * vx.y;
      acc.z += wl[i] * vx.z;
      acc.w += wl[i] * vx.w;
    }
  }

  // publish this block's partial (zeros if no tiles)
  *(float4*)(part + (size_t)blockIdx.x * D_DIM + tid * 4) = acc;
  __threadfence();  // release: partial visible device-wide before ticket

  __shared__ int s_last;
  if (tid == 0) {
    const int old = atomicAdd(&tickets[b], 1);  // device-scope
    s_last = (old == SUBS - 1);
  }
  __syncthreads();

  if (s_last) {
    __threadfence();  // acquire: all 32 partials of batch b now visible
    const float* p = part + ((size_t)b * SUBS) * D_DIM + tid * 4;
    float4 a = make_float4(0.f, 0.f, 0.f, 0.f);
#pragma unroll
    for (int s = 0; s < SUBS; ++s) {
      const float4 vv = *(const float4*)(p + (size_t)s * D_DIM);
      a.x += vv.x;
      a.y += vv.y;
      a.z += vv.z;
      a.w += vv.w;
    }
    *(float4*)(out + (size_t)b * D_DIM + tid * 4) = a;
  }
}

extern "C" void kernel_launch(void* const* d_in, const int* in_sizes, int n_in,
                              void* d_out, int out_size, void* d_ws, size_t ws_size,
                              hipStream_t stream) {
  const float* feat = (const float*)d_in[0];
  const int* lengths = (const int*)d_in[1];
  const int* vq = (const int*)d_in[2];
  float* out = (float*)d_out;
  float* w = (float*)d_ws;                    // B*L floats = 128 KiB
  float* part = w + (size_t)B_DIM * L_SEQ;    // 512*768 floats = 1.5 MiB
  int* tickets = (int*)(part + (size_t)GRID_B * D_DIM);  // 16 ints

  const int B = in_sizes[1];  // 16

  vq_weights_kernel<<<B, BLK_A, 0, stream>>>(lengths, vq, w, tickets);
  vq_pool_kernel<<<GRID_B, 192, 0, stream>>>(feat, lengths, w, part, tickets, out);
}

// Round 12
// 25.050 us; speedup vs baseline: 6.6136x; 2.9183x over previous
//
#include <hip/hip_runtime.h>

// VQWeightedAvgPool: out[b,d] = sum_l w[b,l] * feat[b, N-1, l, d]
// w[b,l] = 1 / (n_seg_b * seg_len_b(l)) for l < len_b, else 0.
// feat (B=16, N=13, L=2048, D=768) f32; lengths (B,) int; vq (B, L, 2) int.
//
// R7 structure (best measured: 24.9us), one change: kernel B uses 384
// threads -- tile rows split between two half-blocks (16 rows each),
// LDS-combined. 12 waves/CU instead of 6 for better latency hiding.

#define L_SEQ 2048
#define D_DIM 768
#define N_DIM 13
#define B_DIM 16
#define BLK_A 256
#define PER_A 8                  // 2048 / 256
#define LT 32                    // L-rows per pooling tile
#define HROWS (LT / 2)           // 16 rows per half-block
#define MAX_TILES (L_SEQ / LT)   // 64
#define SUBS 32                  // pooling blocks per batch
#define GRID_B (B_DIM * SUBS)    // 512
#define BLK_B 384

// ---------------- Kernel A: per-batch segment weights (R7-exact) ------------
__global__ __launch_bounds__(BLK_A) void vq_weights_kernel(
    const int* __restrict__ lengths,
    const int* __restrict__ vq,
    float* __restrict__ w) {
  __shared__ int s_seg[L_SEQ];   // inclusive cumsum of boundary (= seg_id+1)
  __shared__ int s_cnt[L_SEQ];   // per-segment valid counts
  __shared__ int s_wsum[4];

  const int b = blockIdx.x;
  const int tid = threadIdx.x;
  const int lane = tid & 63;
  const int wid = tid >> 6;
  const int len = lengths[b];
  const int* vqb = vq + (size_t)b * L_SEQ * 2;

  // vectorized pair loads: thread t owns l in [8t, 8t+8)
  int4 q[4];
  const int4* v4 = (const int4*)vqb;
#pragma unroll
  for (int i = 0; i < 4; ++i) q[i] = v4[4 * tid + i];
  int px = 0, py = 0;
  if (tid > 0) {
    const int2 pp = *(const int2*)(vqb + 16 * tid - 2);  // pair of l = 8t-1
    px = pp.x; py = pp.y;
  }
  int cx[PER_A], cy[PER_A];
  cx[0] = q[0].x; cy[0] = q[0].y; cx[1] = q[0].z; cy[1] = q[0].w;
  cx[2] = q[1].x; cy[2] = q[1].y; cx[3] = q[1].z; cy[3] = q[1].w;
  cx[4] = q[2].x; cy[4] = q[2].y; cx[5] = q[2].z; cy[5] = q[2].w;
  cx[6] = q[3].x; cy[6] = q[3].y; cx[7] = q[3].z; cy[7] = q[3].w;

  int flags[PER_A];
  const int base = tid * PER_A;
  int lsum = 0;
#pragma unroll
  for (int i = 0; i < PER_A; ++i) {
    const int l = base + i;
    int bd = 0;
    if (l < len) {
      if (l == 0) {
        bd = 1;
      } else {
        const int prx = (i == 0) ? px : cx[i - 1];
        const int pry = (i == 0) ? py : cy[i - 1];
        bd = (cx[i] != prx) || (cy[i] != pry);
      }
    }
    lsum += bd;
    flags[i] = lsum;
  }

  int v = lsum;
  for (int off = 1; off < 64; off <<= 1) {
    int n = __shfl_up(v, off, 64);
    if (lane >= off) v += n;
  }
  if (lane == 63) s_wsum[wid] = v;
  __syncthreads();

  int woff = 0;
#pragma unroll
  for (int i = 0; i < 4; ++i)
    if (i < wid) woff += s_wsum[i];
  const int nseg = s_wsum[0] + s_wsum[1] + s_wsum[2] + s_wsum[3];
  const int excl = woff + (v - lsum);

#pragma unroll
  for (int i = 0; i < PER_A; ++i) s_seg[base + i] = excl + flags[i];
  for (int l = tid; l < L_SEQ; l += BLK_A) s_cnt[l] = 0;
  __syncthreads();

  for (int l = tid; l < L_SEQ; l += BLK_A)
    if (l < len) atomicAdd(&s_cnt[s_seg[l] - 1], 1);
  __syncthreads();

  const float nsegf = (float)nseg;
  for (int l = tid; l < L_SEQ; l += BLK_A) {
    float wv = 0.0f;
    if (l < len) {
      const float denom = fmaxf(nsegf * (float)s_cnt[s_seg[l] - 1], 1.0f);
      wv = 1.0f / denom;
    }
    w[(size_t)b * L_SEQ + l] = wv;
  }
}

// ---------------- Kernel B: pooling partials, 384-thread split-rows ---------
// 512 blocks: (b = blk>>5, sub = blk&31); tiles t = sub, sub+32 (< nt).
// half = tid/192 owns rows [half*16, half*16+16) of each tile; htid = tid%192
// owns float4 at d = 4*htid. LDS-combine halves, then ONE f4 store to part.
__global__ __launch_bounds__(BLK_B) void vq_pool_kernel(
    const float* __restrict__ feat,
    const int* __restrict__ lengths,
    const float* __restrict__ w,
    float* __restrict__ part) {
  __shared__ float4 s_half[D_DIM / 4];  // 3 KB

  const int b = blockIdx.x >> 5;
  const int sub = blockIdx.x & (SUBS - 1);
  const int tid = threadIdx.x;
  const int half = tid / 192;
  const int htid = tid - half * 192;
  const int len = lengths[b];
  int nt = (len + LT - 1) / LT;
  if (nt > MAX_TILES) nt = MAX_TILES;

  const float* fb = feat + ((size_t)b * N_DIM + (N_DIM - 1)) * L_SEQ * D_DIM;
  const float* wb = w + (size_t)b * L_SEQ;

  float4 acc = make_float4(0.f, 0.f, 0.f, 0.f);
  for (int t = sub; t < nt; t += SUBS) {
    const int l0 = t * LT + half * HROWS;
    // this half's 16 weights (uniform across lanes)
    const float4* wb4 = (const float4*)(wb + l0);
    float wl[HROWS];
#pragma unroll
    for (int i = 0; i < HROWS / 4; ++i) {
      const float4 wv = wb4[i];
      wl[4 * i + 0] = wv.x;
      wl[4 * i + 1] = wv.y;
      wl[4 * i + 2] = wv.z;
      wl[4 * i + 3] = wv.w;
    }
    // 16 independent unconditional float4 row loads
    const float* basep = fb + (size_t)l0 * D_DIM + htid * 4;
#pragma unroll
    for (int i = 0; i < HROWS; ++i) {
      const float4 vx = *(const float4*)(basep + (size_t)i * D_DIM);
      acc.x += wl[i] * vx.x;
      acc.y += wl[i] * vx.y;
      acc.z += wl[i] * vx.z;
      acc.w += wl[i] * vx.w;
    }
  }

  // combine halves via LDS, lower half stores the partial
  if (half == 1) s_half[htid] = acc;
  __syncthreads();
  if (half == 0) {
    const float4 o = s_half[htid];
    acc.x += o.x;
    acc.y += o.y;
    acc.z += o.z;
    acc.w += o.w;
    *(float4*)(part + (size_t)blockIdx.x * D_DIM + htid * 4) = acc;
  }
}

// ---------------- Kernel C: reduce 32 partials -> out (R7-exact) ------------
__global__ __launch_bounds__(64) void vq_reduce_kernel(
    const float* __restrict__ part,
    float* __restrict__ out) {
  const int slot = blockIdx.x * 64 + threadIdx.x;  // f4 index into out
  const int b = slot / (D_DIM / 4);
  const int d4 = slot - b * (D_DIM / 4);

  const float* p = part + ((size_t)b * SUBS) * D_DIM + d4 * 4;
  float4 acc = make_float4(0.f, 0.f, 0.f, 0.f);
#pragma unroll
  for (int s = 0; s < SUBS; ++s) {
    const float4 v = *(const float4*)(p + (size_t)s * D_DIM);
    acc.x += v.x;
    acc.y += v.y;
    acc.z += v.z;
    acc.w += v.w;
  }
  *(float4*)(out + (size_t)b * D_DIM + d4 * 4) = acc;
}

extern "C" void kernel_launch(void* const* d_in, const int* in_sizes, int n_in,
                              void* d_out, int out_size, void* d_ws, size_t ws_size,
                              hipStream_t stream) {
  const float* feat = (const float*)d_in[0];
  const int* lengths = (const int*)d_in[1];
  const int* vq = (const int*)d_in[2];
  float* out = (float*)d_out;
  float* w = (float*)d_ws;                  // B*L floats = 128 KiB
  float* part = w + (size_t)B_DIM * L_SEQ;  // 512*768 floats = 1.5 MiB

  const int B = in_sizes[1];  // 16

  vq_weights_kernel<<<B, BLK_A, 0, stream>>>(lengths, vq, w);
  vq_pool_kernel<<<GRID_B, BLK_B, 0, stream>>>(feat, lengths, w, part);
  vq_reduce_kernel<<<(B * D_DIM / 4) / 64, 64, 0, stream>>>(part, out);
}